// Round 1
// baseline (129.724 us; speedup 1.0000x reference)
//
#include <hip/hip_runtime.h>
#include <hip/hip_bf16.h>

// 1x1024x32x32: SE block + separable-gaussian spatial pool + 3x3 local softmax
// attention + 1x1 conv/BN/ReLU.  Round 9: 4 launches.
//   k_A     : per-channel mean + Wb=bf16(W) + K2 gaussian table + xb=bf16(x)
//   k_prep  : per-block redundant SE MLP (w1 is L2-resident) -> y2 slice,
//             then xrb[p][c] = bf16(sigmoid(x*y2[c]))  (transpose via LDS).
//             Kills the separate k_se launch + its pipeline bubble.
//   k_spattn: blocks 0..255   spatial GEMM, A from K2, B from xb (pure bf16
//             copies, no in-loop f2bf VALU), *y2 in epilogue
//             blocks 256..1279 attention on coalesced xrb rows (bf16 LDS)
//   k_main  : bf16 MFMA GEMM, 512 threads / 8 waves (2 waves/SIMD for latency
//             hiding), double-buffered LDS, BN + ReLU
// Lessons pinned: grid.sync ~60us/sync on 8 XCDs (r5) — never cooperative.
//                 inline-sigmoid attention = 9.4M scattered 4B loads (r6) —
//                 always transpose once, then read rows.

typedef __attribute__((ext_vector_type(8))) short v8s;
typedef __attribute__((ext_vector_type(4))) float v4f;

__device__ __forceinline__ float sigmoidf_(float v) {
    return 1.f / (1.f + __expf(-v));
}
__device__ __forceinline__ unsigned short f2bf(float f) {
    unsigned u = __float_as_uint(f);
    u += 0x7fffu + ((u >> 16) & 1u);
    return (unsigned short)(u >> 16);
}
__device__ __forceinline__ float bf2f(unsigned short s) {
    return __uint_as_float(((unsigned)s) << 16);
}

// ---------------- K1: mean + Wb pack + K2 gaussian table + xb pack ----------------
__global__ __launch_bounds__(256) void k_A(const float* __restrict__ x,
                                           const float* __restrict__ W,
                                           float* __restrict__ mean,
                                           unsigned short* __restrict__ Wb,
                                           unsigned short* __restrict__ K2,
                                           unsigned short* __restrict__ xb) {
    __shared__ float Gs[32][32];
    int tid = threadIdx.x, bx = blockIdx.x;
    int wv = tid >> 6, lane = tid & 63;
    // normalized 1-D gaussian table (cheap, per block)
    {
        int row = tid >> 3, col0 = (tid & 7) << 2;
        float e[4], s = 0.f;
        #pragma unroll
        for (int j = 0; j < 4; ++j) {
            float d = (float)(row - (col0 + j));
            e[j] = __expf(-d * d / 4.5f);
            s += e[j];
        }
        s += __shfl_xor(s, 4, 8);
        s += __shfl_xor(s, 2, 8);
        s += __shfl_xor(s, 1, 8);
        float is = 1.f / s;
        #pragma unroll
        for (int j = 0; j < 4; ++j) Gs[row][col0 + j] = e[j] * is;
    }
    // W pack: 2M elements, 8 coalesced chunks
    #pragma unroll
    for (int k = 0; k < 8; ++k) {
        int e = (k << 18) + (bx << 10) + (tid << 2);
        float4 v = *(const float4*)(W + e);
        uint2 pk;
        pk.x = (unsigned)f2bf(v.x) | ((unsigned)f2bf(v.y) << 16);
        pk.y = (unsigned)f2bf(v.z) | ((unsigned)f2bf(v.w) << 16);
        *(uint2*)(Wb + e) = pk;
    }
    // channel c = 4*bx+wv: mean + bf16 pack of the same loaded values
    int c = (bx << 2) + wv;
    const float* xp = x + (size_t)c * 1024;
    float4 vj[4];
    float s = 0.f;
    #pragma unroll
    for (int j = 0; j < 4; ++j) {
        vj[j] = *(const float4*)(xp + (j << 8) + (lane << 2));
        s += vj[j].x + vj[j].y + vj[j].z + vj[j].w;
    }
    #pragma unroll
    for (int o = 32; o; o >>= 1) s += __shfl_down(s, o);
    if (lane == 0) mean[c] = s * (1.f / 1024.f);
    #pragma unroll
    for (int j = 0; j < 4; ++j) {
        uint2 pk;
        pk.x = (unsigned)f2bf(vj[j].x) | ((unsigned)f2bf(vj[j].y) << 16);
        pk.y = (unsigned)f2bf(vj[j].z) | ((unsigned)f2bf(vj[j].w) << 16);
        *(uint2*)(xb + (size_t)c * 1024 + (j << 8) + (lane << 2)) = pk;
    }
    // K2 row p = 4*bx+wv: K2[p][hw] = Gs[p>>5][hw>>5] * Gs[p&31][hw&31]
    __syncthreads();
    {
        int p = (bx << 2) + wv;
        float gr = Gs[p >> 5][lane >> 1];
        const float* gq = &Gs[p & 31][(lane & 1) << 4];
        unsigned pk[8];
        #pragma unroll
        for (int t = 0; t < 8; ++t) {
            float v0 = gr * gq[2 * t];
            float v1 = gr * gq[2 * t + 1];
            pk[t] = (unsigned)f2bf(v0) | ((unsigned)f2bf(v1) << 16);
        }
        unsigned short* dst = K2 + (size_t)p * 1024 + (lane << 4);
        *(uint4*)dst = *(uint4*)&pk[0];
        *(uint4*)(dst + 8) = *(uint4*)&pk[4];
    }
}

// ---------------- K2: redundant SE MLP + transpose, grid (16,16) x 256 ----------------
__global__ __launch_bounds__(256) void k_prep(const float* __restrict__ x,
                                              const float* __restrict__ mean,
                                              const float* __restrict__ w1,
                                              const float* __restrict__ b1,
                                              const float* __restrict__ w2,
                                              const float* __restrict__ b2,
                                              unsigned short* __restrict__ xrb,
                                              float* __restrict__ y2out) {
    __shared__ float ms[1024];
    __shared__ float y1s[64];
    __shared__ float y2s[64];
    __shared__ float T[64][65];
    int tid = threadIdx.x;
    int p0 = blockIdx.x << 6, c0 = blockIdx.y << 6;
    // stage mean
    *(float4*)&ms[tid << 2] = *(const float4*)(mean + (tid << 2));
    __syncthreads();
    int wv = tid >> 6, lane = tid & 63;
    // y1[j] = relu(w1[j,:] . mean + b1[j]); wave wv owns j = wv*16 .. +15
    #pragma unroll
    for (int jj = 0; jj < 16; ++jj) {
        int j = (wv << 4) + jj;
        float s = 0.f;
        #pragma unroll
        for (int kk = 0; kk < 4; ++kk) {
            float4 wv4 = *(const float4*)(w1 + (size_t)j * 1024 + kk * 256 + (lane << 2));
            float4 mv  = *(const float4*)&ms[kk * 256 + (lane << 2)];
            s += wv4.x * mv.x + wv4.y * mv.y + wv4.z * mv.z + wv4.w * mv.w;
        }
        #pragma unroll
        for (int o = 32; o; o >>= 1) s += __shfl_down(s, o);
        if (lane == 0) y1s[j] = fmaxf(s + b1[j], 0.f);
    }
    __syncthreads();
    // y2[c0+ci] = sigmoid(w2[c0+ci,:] . y1 + b2); 4 lanes per channel
    {
        int ci = tid >> 2, sub = tid & 3;
        float s = 0.f;
        const float* w2r = w2 + (size_t)(c0 + ci) * 64 + sub * 16;
        #pragma unroll
        for (int i = 0; i < 4; ++i) {
            float4 wv4 = *(const float4*)(w2r + (i << 2));
            float4 yv4 = *(const float4*)&y1s[sub * 16 + (i << 2)];
            s += wv4.x * yv4.x + wv4.y * yv4.y + wv4.z * yv4.z + wv4.w * yv4.w;
        }
        s += __shfl_down(s, 2, 4);
        s += __shfl_down(s, 1, 4);
        if (sub == 0) y2s[ci] = sigmoidf_(s + b2[c0 + ci]);
    }
    __syncthreads();
    if (blockIdx.x == 0 && tid < 64) y2out[c0 + tid] = y2s[tid];
    // transpose: xrb[p0+prow][c0+cc] = bf16(sigmoid(x[c][p]*y2[c]))
    #pragma unroll
    for (int i = 0; i < 4; ++i) {
        int idx = tid + (i << 8);
        int row = idx >> 4;
        int col = (idx & 15) << 2;
        float sc = y2s[row];
        float4 v = *(const float4*)(x + (size_t)(c0 + row) * 1024 + p0 + col);
        T[col + 0][row] = sigmoidf_(v.x * sc);
        T[col + 1][row] = sigmoidf_(v.y * sc);
        T[col + 2][row] = sigmoidf_(v.z * sc);
        T[col + 3][row] = sigmoidf_(v.w * sc);
    }
    __syncthreads();
    #pragma unroll
    for (int i = 0; i < 4; ++i) {
        int idx = tid + (i << 8);
        int prow = idx >> 4;
        int cc = (idx & 15) << 2;
        uint2 pk;
        pk.x = (unsigned)f2bf(T[prow][cc + 0]) | ((unsigned)f2bf(T[prow][cc + 1]) << 16);
        pk.y = (unsigned)f2bf(T[prow][cc + 2]) | ((unsigned)f2bf(T[prow][cc + 3]) << 16);
        *(uint2*)(xrb + (size_t)(p0 + prow) * 1024 + c0 + cc) = pk;
    }
}

// ---------------- K3: fused spatial GEMM + attention ----------------
union __align__(16) SMem {
    struct { unsigned short As[64 * 72]; unsigned short Bs[64 * 72]; } sp;  // 18 KB
    struct { unsigned short val[9216]; float part[9][4]; } at;              // 18.6 KB
};

__global__ __launch_bounds__(256) void k_spattn(const unsigned short* __restrict__ xb,
                                                const unsigned short* __restrict__ xrb,
                                                const unsigned short* __restrict__ K2,
                                                const float* __restrict__ y2,
                                                unsigned short* __restrict__ Bt) {
    __shared__ SMem sm;
    int tid = threadIdx.x;
    int bx = blockIdx.x;
    int wv = tid >> 6, lane = tid & 63;
    if (bx < 256) {
        // spatial GEMM: Bt[p][1024+c] = y2[c] * sum_hw K2[p][hw]*xb[c][hw]
        int wm = wv & 1, wn = wv >> 1;
        int m0 = (bx >> 4) << 6, n0 = (bx & 15) << 6;
        int col = lane & 15, quad = lane >> 4;
        int smi = tid >> 2;
        int sg = (tid & 3) * 2;
        v4f acc[2][2];
        #pragma unroll
        for (int i = 0; i < 2; ++i)
            #pragma unroll
            for (int j = 0; j < 2; ++j) acc[i][j] = (v4f){0.f, 0.f, 0.f, 0.f};
        const float4* pa = (const float4*)(K2 + (size_t)(m0 + smi) * 1024 + sg * 8);
        const float4* pb = (const float4*)(xb + (size_t)(n0 + smi) * 1024 + sg * 8);
        float4 ka0 = pa[0], ka1 = pa[1];
        float4 kb0 = pb[0], kb1 = pb[1];
        for (int it = 0; it < 16; ++it) {
            __syncthreads();
            *(float4*)&sm.sp.As[smi * 72 + sg * 8] = ka0;
            *(float4*)&sm.sp.As[smi * 72 + sg * 8 + 8] = ka1;
            *(float4*)&sm.sp.Bs[smi * 72 + sg * 8] = kb0;
            *(float4*)&sm.sp.Bs[smi * 72 + sg * 8 + 8] = kb1;
            __syncthreads();
            if (it + 1 < 16) {
                int k0 = (it + 1) << 6;
                pa = (const float4*)(K2 + (size_t)(m0 + smi) * 1024 + k0 + sg * 8);
                pb = (const float4*)(xb + (size_t)(n0 + smi) * 1024 + k0 + sg * 8);
                ka0 = pa[0]; ka1 = pa[1];
                kb0 = pb[0]; kb1 = pb[1];
            }
            #pragma unroll
            for (int ks = 0; ks < 2; ++ks) {
                int kg = ks * 4 + quad;
                int rA = wm * 32 + col;
                int rB = wn * 32 + col;
                v8s a0 = *(const v8s*)&sm.sp.As[rA * 72 + kg * 8];
                v8s a1 = *(const v8s*)&sm.sp.As[(rA + 16) * 72 + kg * 8];
                v8s b0 = *(const v8s*)&sm.sp.Bs[rB * 72 + kg * 8];
                v8s b1 = *(const v8s*)&sm.sp.Bs[(rB + 16) * 72 + kg * 8];
                acc[0][0] = __builtin_amdgcn_mfma_f32_16x16x32_bf16(a0, b0, acc[0][0], 0, 0, 0);
                acc[0][1] = __builtin_amdgcn_mfma_f32_16x16x32_bf16(a0, b1, acc[0][1], 0, 0, 0);
                acc[1][0] = __builtin_amdgcn_mfma_f32_16x16x32_bf16(a1, b0, acc[1][0], 0, 0, 0);
                acc[1][1] = __builtin_amdgcn_mfma_f32_16x16x32_bf16(a1, b1, acc[1][1], 0, 0, 0);
            }
        }
        #pragma unroll
        for (int mi = 0; mi < 2; ++mi)
            #pragma unroll
            for (int ni = 0; ni < 2; ++ni) {
                int mb = m0 + wm * 32 + mi * 16 + quad * 4;
                int nn = n0 + wn * 32 + ni * 16 + col;
                float yv = y2[nn];               // SE scale commuted past the pool
                #pragma unroll
                for (int r = 0; r < 4; ++r)
                    Bt[(size_t)(mb + r) * 2048 + 1024 + nn] = f2bf(acc[mi][ni][r] * yv);
            }
    } else {
        // attention, position p = bx-256, coalesced bf16 xrb rows.
        // val[f] with f = 9*cf+rem == 1024*q + c2 (reference reshape reinterpretation).
        int p = bx - 256;
        int h = p >> 5, w = p & 31;
        #pragma unroll
        for (int rem = 0; rem < 9; ++rem) {
            int dh = rem / 3 - 1, dw = rem % 3 - 1;
            bool ok = ((unsigned)(h + dh) < 32u) && ((unsigned)(w + dw) < 32u);
            const unsigned short* rp = xrb + (size_t)((h + dh) * 32 + (w + dw)) * 1024;
            #pragma unroll
            for (int j = 0; j < 4; ++j) {
                int cf = tid + (j << 8);
                sm.at.val[cf * 9 + rem] = ok ? rp[cf] : (unsigned short)0;
            }
        }
        __syncthreads();
        float ctr[4], vvq[9][4], lg[9];
        #pragma unroll
        for (int j = 0; j < 4; ++j) ctr[j] = bf2f(sm.at.val[(4 * tid + j) * 9 + 4]);
        #pragma unroll
        for (int q = 0; q < 9; ++q) {
            uint2 pk = *(const uint2*)&sm.at.val[(q << 10) + 4 * tid];
            vvq[q][0] = bf2f((unsigned short)(pk.x & 0xffffu));
            vvq[q][1] = bf2f((unsigned short)(pk.x >> 16));
            vvq[q][2] = bf2f((unsigned short)(pk.y & 0xffffu));
            vvq[q][3] = bf2f((unsigned short)(pk.y >> 16));
            lg[q] = ctr[0] * vvq[q][0] + ctr[1] * vvq[q][1]
                  + ctr[2] * vvq[q][2] + ctr[3] * vvq[q][3];
        }
        #pragma unroll
        for (int q = 0; q < 9; ++q) {
            float s = lg[q];
            #pragma unroll
            for (int o = 32; o; o >>= 1) s += __shfl_down(s, o);
            if (lane == 0) sm.at.part[q][wv] = s;
        }
        __syncthreads();
        float a9[9], mx = -3.4e38f;
        #pragma unroll
        for (int q = 0; q < 9; ++q) {
            a9[q] = sm.at.part[q][0] + sm.at.part[q][1] + sm.at.part[q][2] + sm.at.part[q][3];
            mx = fmaxf(mx, a9[q]);
        }
        float se = 0.f;
        #pragma unroll
        for (int q = 0; q < 9; ++q) { a9[q] = __expf(a9[q] - mx); se += a9[q]; }
        float inv = 1.f / se;
        float o4[4] = {0.f, 0.f, 0.f, 0.f};
        #pragma unroll
        for (int q = 0; q < 9; ++q) {
            float a = a9[q] * inv;
            #pragma unroll
            for (int j = 0; j < 4; ++j) o4[j] += a * vvq[q][j];
        }
        uint2 pk;
        pk.x = (unsigned)f2bf(o4[0]) | ((unsigned)f2bf(o4[1]) << 16);
        pk.y = (unsigned)f2bf(o4[2]) | ((unsigned)f2bf(o4[3]) << 16);
        *(uint2*)(Bt + (size_t)p * 2048 + 4 * tid) = pk;
    }
}

// ---------------- K4: main GEMM, 8 waves (2/SIMD), double-buffered LDS, BN + ReLU ----------------
__global__ __launch_bounds__(512) void k_main(
    const unsigned short* __restrict__ A, const unsigned short* __restrict__ B,
    float* __restrict__ outF,
    const float* __restrict__ gamma, const float* __restrict__ beta,
    const float* __restrict__ mu, const float* __restrict__ var) {
    __shared__ unsigned short As[2][64 * 72];
    __shared__ unsigned short Bs[2][64 * 72];
    const int K = 2048;
    int tid = threadIdx.x;
    int wv = tid >> 6, lane = tid & 63;
    int wm = wv & 3, wn = wv >> 2;          // 4 (M) x 2 (N) wave grid
    int m0 = blockIdx.y << 6, n0 = blockIdx.x << 6;
    int col = lane & 15, quad = lane >> 4;
    int srow = tid >> 3;                    // stage row 0..63
    int schunk = tid & 7;                   // stage chunk of 8 bf16
    v4f acc[2];
    acc[0] = (v4f){0.f, 0.f, 0.f, 0.f};
    acc[1] = (v4f){0.f, 0.f, 0.f, 0.f};

    const float4* pa = (const float4*)(A + (size_t)(m0 + srow) * K + schunk * 8);
    const float4* pb = (const float4*)(B + (size_t)(n0 + srow) * K + schunk * 8);
    float4 ra = pa[0], rb = pb[0];
    *(float4*)&As[0][srow * 72 + schunk * 8] = ra;
    *(float4*)&Bs[0][srow * 72 + schunk * 8] = rb;
    for (int it = 0; it < 32; ++it) {
        __syncthreads();
        int cur = it & 1;
        if (it + 1 < 32) {
            int k0 = (it + 1) << 6;
            pa = (const float4*)(A + (size_t)(m0 + srow) * K + k0 + schunk * 8);
            pb = (const float4*)(B + (size_t)(n0 + srow) * K + k0 + schunk * 8);
            ra = pa[0]; rb = pb[0];
        }
        #pragma unroll
        for (int ks = 0; ks < 2; ++ks) {
            int kg = ks * 4 + quad;
            int rA = wm * 16 + col;
            int rB = wn * 32 + col;
            v8s a  = *(const v8s*)&As[cur][rA * 72 + kg * 8];
            v8s b0 = *(const v8s*)&Bs[cur][rB * 72 + kg * 8];
            v8s b1 = *(const v8s*)&Bs[cur][(rB + 16) * 72 + kg * 8];
            acc[0] = __builtin_amdgcn_mfma_f32_16x16x32_bf16(a, b0, acc[0], 0, 0, 0);
            acc[1] = __builtin_amdgcn_mfma_f32_16x16x32_bf16(a, b1, acc[1], 0, 0, 0);
        }
        if (it + 1 < 32) {
            int nxt = cur ^ 1;
            *(float4*)&As[nxt][srow * 72 + schunk * 8] = ra;
            *(float4*)&Bs[nxt][srow * 72 + schunk * 8] = rb;
        }
    }
    #pragma unroll
    for (int ni = 0; ni < 2; ++ni) {
        int mb = m0 + wm * 16 + quad * 4;
        int nn = n0 + wn * 32 + ni * 16 + col;
        #pragma unroll
        for (int r = 0; r < 4; ++r) {
            int mm = mb + r;
            float iv = rsqrtf(var[mm] + 1e-5f);
            float sc = iv * gamma[mm];
            float sh = beta[mm] - mu[mm] * sc;
            outF[((size_t)mm << 10) + nn] = fmaxf(fmaf(acc[ni][r], sc, sh), 0.f);
        }
    }
}

extern "C" void kernel_launch(void* const* d_in, const int* in_sizes, int n_in,
                              void* d_out, int out_size, void* d_ws, size_t ws_size,
                              hipStream_t stream) {
    const float* x     = (const float*)d_in[0];
    const float* w1    = (const float*)d_in[1];
    const float* b1    = (const float*)d_in[2];
    const float* w2    = (const float*)d_in[3];
    const float* b2    = (const float*)d_in[4];
    const float* cw    = (const float*)d_in[5];
    const float* gamma = (const float*)d_in[6];
    const float* beta  = (const float*)d_in[7];
    const float* mu    = (const float*)d_in[8];
    const float* var   = (const float*)d_in[9];
    float* wsf = (float*)d_ws;
    unsigned short* Wb  = (unsigned short*)wsf;                 // 4 MB [1024][2048]
    unsigned short* Bt  = (unsigned short*)(wsf + (1 << 20));   // 4 MB [1024][2048]
    unsigned short* xrb = (unsigned short*)(wsf + (2 << 20));   // 2 MB [p][c]
    unsigned short* K2  = (unsigned short*)(wsf + (2 << 20) + (1 << 19)); // 2 MB [p][hw]
    float* mean = wsf + (3 << 20);
    float* y2   = mean + 1024;
    unsigned short* xb = (unsigned short*)(y2 + 1024);          // 2 MB [c][hw] bf16
    float* out  = (float*)d_out;

    dim3 g16(16, 16);
    k_A     <<<256, 256, 0, stream>>>(x, cw, mean, Wb, K2, xb);
    k_prep  <<<g16, 256, 0, stream>>>(x, mean, w1, b1, w2, b2, xrb, y2);
    k_spattn<<<1280, 256, 0, stream>>>(xb, xrb, K2, y2, Bt);
    k_main  <<<g16, 512, 0, stream>>>(Wb, Bt, out, gamma, beta, mu, var);
}

// Round 2
// 123.023 us; speedup vs baseline: 1.0545x; 1.0545x over previous
//
#include <hip/hip_runtime.h>
#include <hip/hip_bf16.h>

// 1x1024x32x32: SE block + separable-gaussian spatial pool + 3x3 local softmax
// attention + 1x1 conv/BN/ReLU.  Round 10: 4 launches, spatial GEMM removed.
//   k_A     : per-channel mean + Wb=bf16(W) + BN scale/shift precompute +
//             SEPARABLE gaussian pool: U[c][p] = sum_h G[ph,h] sum_w G[pw,w] x[c,h,w]
//             (2 MFMA stages per wave/channel; kills the 1024^3 spatial GEMM,
//              the K2 table, and the xb pack)
//   k_prep  : per-block redundant SE MLP -> y2; xrb[p][c]=bf16(sigmoid(x*y2));
//             U tile transpose * y2 -> Bt spatial half (SE commutes past pool)
//   k_attn  : 3x3 softmax attention on coalesced xrb rows -> Bt attention half
//   k_main  : bf16 MFMA GEMM (XCD-swizzled blocks, dbuf LDS) + BN + ReLU
// Lessons pinned: grid.sync ~60us/sync on 8 XCDs (r5) — never cooperative.
//                 inline-sigmoid attention = 9.4M scattered 4B loads (r6) —
//                 always transpose once, then read rows.
//                 measured dur includes ~89us fixed harness poison fills (r9) —
//                 only structural work removal moves the needle.

typedef __attribute__((ext_vector_type(8))) short v8s;
typedef __attribute__((ext_vector_type(4))) float v4f;

__device__ __forceinline__ float sigmoidf_(float v) {
    return 1.f / (1.f + __expf(-v));
}
__device__ __forceinline__ unsigned short f2bf(float f) {
    unsigned u = __float_as_uint(f);
    u += 0x7fffu + ((u >> 16) & 1u);
    return (unsigned short)(u >> 16);
}
__device__ __forceinline__ float bf2f(unsigned short s) {
    return __uint_as_float(((unsigned)s) << 16);
}

// ---------------- K1: mean + Wb pack + BN precompute + separable pool ----------------
__global__ __launch_bounds__(256) void k_A(const float* __restrict__ x,
                                           const float* __restrict__ W,
                                           const float* __restrict__ gamma,
                                           const float* __restrict__ beta,
                                           const float* __restrict__ mu,
                                           const float* __restrict__ var,
                                           float* __restrict__ mean,
                                           unsigned short* __restrict__ Wb,
                                           unsigned short* __restrict__ U,
                                           float* __restrict__ bnsc,
                                           float* __restrict__ bnsh) {
    __shared__ unsigned short Gb[32 * 48];       // bf16 normalized 1-D gaussian
    __shared__ unsigned short Xs[4][32 * 48];    // per-wave channel tile bf16
    __shared__ unsigned short Ts[4][32 * 48];    // per-wave stage-1 result bf16
    int tid = threadIdx.x, bx = blockIdx.x;
    int wv = tid >> 6, lane = tid & 63;
    // normalized 1-D gaussian row chunk (each thread writes its own values)
    {
        int row = tid >> 3, col0 = (tid & 7) << 2;
        float e[4], s = 0.f;
        #pragma unroll
        for (int j = 0; j < 4; ++j) {
            float d = (float)(row - (col0 + j));
            e[j] = __expf(-d * d / 4.5f);
            s += e[j];
        }
        s += __shfl_xor(s, 4, 8);
        s += __shfl_xor(s, 2, 8);
        s += __shfl_xor(s, 1, 8);
        float is = 1.f / s;
        uint2 pk;
        pk.x = (unsigned)f2bf(e[0] * is) | ((unsigned)f2bf(e[1] * is) << 16);
        pk.y = (unsigned)f2bf(e[2] * is) | ((unsigned)f2bf(e[3] * is) << 16);
        *(uint2*)&Gb[row * 48 + col0] = pk;
    }
    // W pack: 2M elements, 8 coalesced chunks
    #pragma unroll
    for (int k = 0; k < 8; ++k) {
        int e = (k << 18) + (bx << 10) + (tid << 2);
        float4 v = *(const float4*)(W + e);
        uint2 pk;
        pk.x = (unsigned)f2bf(v.x) | ((unsigned)f2bf(v.y) << 16);
        pk.y = (unsigned)f2bf(v.z) | ((unsigned)f2bf(v.w) << 16);
        *(uint2*)(Wb + e) = pk;
    }
    // channel c = 4*bx+wv
    int c = (bx << 2) + wv;
    // BN precompute (one lane per channel)
    if (lane == 0) {
        float iv = rsqrtf(var[c] + 1e-5f);
        float sc = iv * gamma[c];
        bnsc[c] = sc;
        bnsh[c] = beta[c] - mu[c] * sc;
    }
    // x load + mean + Xs bf16 pack (h = j*8 + lane>>3, w0 = (lane&7)*4)
    const float* xp = x + (size_t)c * 1024;
    float4 vj[4];
    float s = 0.f;
    #pragma unroll
    for (int j = 0; j < 4; ++j) {
        vj[j] = *(const float4*)(xp + (j << 8) + (lane << 2));
        s += vj[j].x + vj[j].y + vj[j].z + vj[j].w;
    }
    #pragma unroll
    for (int o = 32; o; o >>= 1) s += __shfl_down(s, o);
    if (lane == 0) mean[c] = s * (1.f / 1024.f);
    #pragma unroll
    for (int j = 0; j < 4; ++j) {
        int h = (j << 3) + (lane >> 3);
        int w0 = (lane & 7) << 2;
        uint2 pk;
        pk.x = (unsigned)f2bf(vj[j].x) | ((unsigned)f2bf(vj[j].y) << 16);
        pk.y = (unsigned)f2bf(vj[j].z) | ((unsigned)f2bf(vj[j].w) << 16);
        *(uint2*)&Xs[wv][h * 48 + w0] = pk;
    }
    __syncthreads();
    // stage 1: T'[pw][h] = sum_w G[pw,w] * X[h,w]   (one 16x16x32 MFMA per tile)
    int colf = lane & 15, quad = lane >> 4;
    v8s ga[2], xbv[2];
    #pragma unroll
    for (int mi = 0; mi < 2; ++mi)
        ga[mi] = *(const v8s*)&Gb[(mi * 16 + colf) * 48 + quad * 8];
    #pragma unroll
    for (int ni = 0; ni < 2; ++ni)
        xbv[ni] = *(const v8s*)&Xs[wv][(ni * 16 + colf) * 48 + quad * 8];
    v4f c1[2][2];
    #pragma unroll
    for (int mi = 0; mi < 2; ++mi)
        #pragma unroll
        for (int ni = 0; ni < 2; ++ni) {
            c1[mi][ni] = (v4f){0.f, 0.f, 0.f, 0.f};
            c1[mi][ni] = __builtin_amdgcn_mfma_f32_16x16x32_bf16(ga[mi], xbv[ni], c1[mi][ni], 0, 0, 0);
        }
    #pragma unroll
    for (int mi = 0; mi < 2; ++mi)
        #pragma unroll
        for (int ni = 0; ni < 2; ++ni)
            #pragma unroll
            for (int r = 0; r < 4; ++r)
                Ts[wv][(mi * 16 + quad * 4 + r) * 48 + ni * 16 + colf] = f2bf(c1[mi][ni][r]);
    __syncthreads();
    // stage 2: S[ph][pw] = sum_h G[ph,h] * T'[pw,h]  (A-frag ga reused)
    v8s tb[2];
    #pragma unroll
    for (int ni = 0; ni < 2; ++ni)
        tb[ni] = *(const v8s*)&Ts[wv][(ni * 16 + colf) * 48 + quad * 8];
    v4f c2[2][2];
    #pragma unroll
    for (int mi = 0; mi < 2; ++mi)
        #pragma unroll
        for (int ni = 0; ni < 2; ++ni) {
            c2[mi][ni] = (v4f){0.f, 0.f, 0.f, 0.f};
            c2[mi][ni] = __builtin_amdgcn_mfma_f32_16x16x32_bf16(ga[mi], tb[ni], c2[mi][ni], 0, 0, 0);
        }
    // U[c][p], p = ph*32+pw (unscaled; y2 applied in k_prep)
    #pragma unroll
    for (int mi = 0; mi < 2; ++mi)
        #pragma unroll
        for (int ni = 0; ni < 2; ++ni)
            #pragma unroll
            for (int r = 0; r < 4; ++r)
                U[(size_t)c * 1024 + (mi * 16 + quad * 4 + r) * 32 + ni * 16 + colf] =
                    f2bf(c2[mi][ni][r]);
}

// ---------------- K2: redundant SE MLP + transposes, grid (16,16) x 256 ----------------
__global__ __launch_bounds__(256) void k_prep(const float* __restrict__ x,
                                              const float* __restrict__ mean,
                                              const float* __restrict__ w1,
                                              const float* __restrict__ b1,
                                              const float* __restrict__ w2,
                                              const float* __restrict__ b2,
                                              const unsigned short* __restrict__ U,
                                              unsigned short* __restrict__ xrb,
                                              unsigned short* __restrict__ Bt) {
    __shared__ float ms[1024];
    __shared__ float y1s[64];
    __shared__ float y2s[64];
    __shared__ float T[64][65];
    int tid = threadIdx.x;
    int p0 = blockIdx.x << 6, c0 = blockIdx.y << 6;
    *(float4*)&ms[tid << 2] = *(const float4*)(mean + (tid << 2));
    __syncthreads();
    int wv = tid >> 6, lane = tid & 63;
    // y1[j] = relu(w1[j,:] . mean + b1[j]); wave wv owns j = wv*16 .. +15
    #pragma unroll
    for (int jj = 0; jj < 16; ++jj) {
        int j = (wv << 4) + jj;
        float s = 0.f;
        #pragma unroll
        for (int kk = 0; kk < 4; ++kk) {
            float4 wv4 = *(const float4*)(w1 + (size_t)j * 1024 + kk * 256 + (lane << 2));
            float4 mv  = *(const float4*)&ms[kk * 256 + (lane << 2)];
            s += wv4.x * mv.x + wv4.y * mv.y + wv4.z * mv.z + wv4.w * mv.w;
        }
        #pragma unroll
        for (int o = 32; o; o >>= 1) s += __shfl_down(s, o);
        if (lane == 0) y1s[j] = fmaxf(s + b1[j], 0.f);
    }
    __syncthreads();
    // y2[c0+ci] = sigmoid(w2[c0+ci,:] . y1 + b2); 4 lanes per channel
    {
        int ci = tid >> 2, sub = tid & 3;
        float s = 0.f;
        const float* w2r = w2 + (size_t)(c0 + ci) * 64 + sub * 16;
        #pragma unroll
        for (int i = 0; i < 4; ++i) {
            float4 wv4 = *(const float4*)(w2r + (i << 2));
            float4 yv4 = *(const float4*)&y1s[sub * 16 + (i << 2)];
            s += wv4.x * yv4.x + wv4.y * yv4.y + wv4.z * yv4.z + wv4.w * yv4.w;
        }
        s += __shfl_down(s, 2, 4);
        s += __shfl_down(s, 1, 4);
        if (sub == 0) y2s[ci] = sigmoidf_(s + b2[c0 + ci]);
    }
    __syncthreads();
    // pass 1: xrb[p0+prow][c0+cc] = bf16(sigmoid(x[c][p]*y2[c]))
    #pragma unroll
    for (int i = 0; i < 4; ++i) {
        int idx = tid + (i << 8);
        int row = idx >> 4;
        int col = (idx & 15) << 2;
        float sc = y2s[row];
        float4 v = *(const float4*)(x + (size_t)(c0 + row) * 1024 + p0 + col);
        T[col + 0][row] = sigmoidf_(v.x * sc);
        T[col + 1][row] = sigmoidf_(v.y * sc);
        T[col + 2][row] = sigmoidf_(v.z * sc);
        T[col + 3][row] = sigmoidf_(v.w * sc);
    }
    __syncthreads();
    #pragma unroll
    for (int i = 0; i < 4; ++i) {
        int idx = tid + (i << 8);
        int prow = idx >> 4;
        int cc = (idx & 15) << 2;
        uint2 pk;
        pk.x = (unsigned)f2bf(T[prow][cc + 0]) | ((unsigned)f2bf(T[prow][cc + 1]) << 16);
        pk.y = (unsigned)f2bf(T[prow][cc + 2]) | ((unsigned)f2bf(T[prow][cc + 3]) << 16);
        *(uint2*)(xrb + (size_t)(p0 + prow) * 1024 + c0 + cc) = pk;
    }
    __syncthreads();
    // pass 2: Bt[p][1024+c] = bf16(U[c][p] * y2[c])  (spatial half, SE commuted)
    #pragma unroll
    for (int i = 0; i < 4; ++i) {
        int idx = tid + (i << 8);
        int row = idx >> 4;
        int col = (idx & 15) << 2;
        float sc = y2s[row];
        uint2 pk = *(const uint2*)(U + (size_t)(c0 + row) * 1024 + p0 + col);
        T[col + 0][row] = bf2f((unsigned short)(pk.x & 0xffffu)) * sc;
        T[col + 1][row] = bf2f((unsigned short)(pk.x >> 16)) * sc;
        T[col + 2][row] = bf2f((unsigned short)(pk.y & 0xffffu)) * sc;
        T[col + 3][row] = bf2f((unsigned short)(pk.y >> 16)) * sc;
    }
    __syncthreads();
    #pragma unroll
    for (int i = 0; i < 4; ++i) {
        int idx = tid + (i << 8);
        int prow = idx >> 4;
        int cc = (idx & 15) << 2;
        uint2 pk;
        pk.x = (unsigned)f2bf(T[prow][cc + 0]) | ((unsigned)f2bf(T[prow][cc + 1]) << 16);
        pk.y = (unsigned)f2bf(T[prow][cc + 2]) | ((unsigned)f2bf(T[prow][cc + 3]) << 16);
        *(uint2*)(Bt + (size_t)(p0 + prow) * 2048 + 1024 + c0 + cc) = pk;
    }
}

// ---------------- K3: 3x3 softmax attention, 1024 blocks ----------------
__global__ __launch_bounds__(256) void k_attn(const unsigned short* __restrict__ xrb,
                                              unsigned short* __restrict__ Bt) {
    __shared__ struct { unsigned short val[9216]; float part[9][4]; } sm;
    int tid = threadIdx.x;
    int p = blockIdx.x;
    int wv = tid >> 6, lane = tid & 63;
    int h = p >> 5, w = p & 31;
    // val[f] with f = 9*cf+rem == 1024*q + c2 (reference reshape reinterpretation).
    float ctr[4];
    #pragma unroll
    for (int rem = 0; rem < 9; ++rem) {
        int dh = rem / 3 - 1, dw = rem % 3 - 1;
        bool ok = ((unsigned)(h + dh) < 32u) && ((unsigned)(w + dw) < 32u);
        uint2 v = make_uint2(0u, 0u);
        if (ok)
            v = *(const uint2*)(xrb + (size_t)((h + dh) * 32 + (w + dw)) * 1024 + 4 * tid);
        unsigned short e0 = (unsigned short)(v.x & 0xffffu);
        unsigned short e1 = (unsigned short)(v.x >> 16);
        unsigned short e2 = (unsigned short)(v.y & 0xffffu);
        unsigned short e3 = (unsigned short)(v.y >> 16);
        sm.val[(4 * tid + 0) * 9 + rem] = e0;
        sm.val[(4 * tid + 1) * 9 + rem] = e1;
        sm.val[(4 * tid + 2) * 9 + rem] = e2;
        sm.val[(4 * tid + 3) * 9 + rem] = e3;
        if (rem == 4) {
            ctr[0] = bf2f(e0); ctr[1] = bf2f(e1); ctr[2] = bf2f(e2); ctr[3] = bf2f(e3);
        }
    }
    __syncthreads();
    float vvq[9][4], lg[9];
    #pragma unroll
    for (int q = 0; q < 9; ++q) {
        uint2 pk = *(const uint2*)&sm.val[(q << 10) + 4 * tid];
        vvq[q][0] = bf2f((unsigned short)(pk.x & 0xffffu));
        vvq[q][1] = bf2f((unsigned short)(pk.x >> 16));
        vvq[q][2] = bf2f((unsigned short)(pk.y & 0xffffu));
        vvq[q][3] = bf2f((unsigned short)(pk.y >> 16));
        lg[q] = ctr[0] * vvq[q][0] + ctr[1] * vvq[q][1]
              + ctr[2] * vvq[q][2] + ctr[3] * vvq[q][3];
    }
    #pragma unroll
    for (int q = 0; q < 9; ++q) {
        float s = lg[q];
        #pragma unroll
        for (int o = 32; o; o >>= 1) s += __shfl_down(s, o);
        if (lane == 0) sm.part[q][wv] = s;
    }
    __syncthreads();
    float a9[9], mx = -3.4e38f;
    #pragma unroll
    for (int q = 0; q < 9; ++q) {
        a9[q] = sm.part[q][0] + sm.part[q][1] + sm.part[q][2] + sm.part[q][3];
        mx = fmaxf(mx, a9[q]);
    }
    float se = 0.f;
    #pragma unroll
    for (int q = 0; q < 9; ++q) { a9[q] = __expf(a9[q] - mx); se += a9[q]; }
    float inv = 1.f / se;
    float o4[4] = {0.f, 0.f, 0.f, 0.f};
    #pragma unroll
    for (int q = 0; q < 9; ++q) {
        float a = a9[q] * inv;
        #pragma unroll
        for (int j = 0; j < 4; ++j) o4[j] += a * vvq[q][j];
    }
    uint2 pk;
    pk.x = (unsigned)f2bf(o4[0]) | ((unsigned)f2bf(o4[1]) << 16);
    pk.y = (unsigned)f2bf(o4[2]) | ((unsigned)f2bf(o4[3]) << 16);
    *(uint2*)(Bt + (size_t)p * 2048 + 4 * tid) = pk;
}

// ---------------- K4: main GEMM, XCD-swizzled, 8 waves, dbuf LDS, BN + ReLU ----------------
__global__ __launch_bounds__(512) void k_main(
    const unsigned short* __restrict__ A, const unsigned short* __restrict__ B,
    float* __restrict__ outF,
    const float* __restrict__ bnsc, const float* __restrict__ bnsh) {
    __shared__ unsigned short As[2][64 * 72];
    __shared__ unsigned short Bs[2][64 * 72];
    const int K = 2048;
    int tid = threadIdx.x;
    // XCD swizzle: blocks dispatch round-robin over 8 XCDs; give XCD k a 4x8
    // tile rectangle so its L2 footprint is 1MB A + 2MB B instead of ~8MB.
    int bid = blockIdx.x;
    int xcd = bid & 7, idx = bid >> 3;
    int by = ((xcd >> 1) << 2) + (idx >> 3);
    int bxn = ((xcd & 1) << 3) + (idx & 7);
    int m0 = by << 6, n0 = bxn << 6;
    int wv = tid >> 6, lane = tid & 63;
    int wm = wv & 3, wn = wv >> 2;          // 4 (M) x 2 (N) wave grid
    int col = lane & 15, quad = lane >> 4;
    int srow = tid >> 3;                    // stage row 0..63
    int schunk = tid & 7;                   // stage chunk of 8 bf16
    v4f acc[2];
    acc[0] = (v4f){0.f, 0.f, 0.f, 0.f};
    acc[1] = (v4f){0.f, 0.f, 0.f, 0.f};

    const float4* pa = (const float4*)(A + (size_t)(m0 + srow) * K + schunk * 8);
    const float4* pb = (const float4*)(B + (size_t)(n0 + srow) * K + schunk * 8);
    float4 ra = pa[0], rb = pb[0];
    *(float4*)&As[0][srow * 72 + schunk * 8] = ra;
    *(float4*)&Bs[0][srow * 72 + schunk * 8] = rb;
    for (int it = 0; it < 32; ++it) {
        __syncthreads();
        int cur = it & 1;
        if (it + 1 < 32) {
            int k0 = (it + 1) << 6;
            pa = (const float4*)(A + (size_t)(m0 + srow) * K + k0 + schunk * 8);
            pb = (const float4*)(B + (size_t)(n0 + srow) * K + k0 + schunk * 8);
            ra = pa[0]; rb = pb[0];
        }
        #pragma unroll
        for (int ks = 0; ks < 2; ++ks) {
            int kg = ks * 4 + quad;
            int rA = wm * 16 + col;
            int rB = wn * 32 + col;
            v8s a  = *(const v8s*)&As[cur][rA * 72 + kg * 8];
            v8s b0 = *(const v8s*)&Bs[cur][rB * 72 + kg * 8];
            v8s b1 = *(const v8s*)&Bs[cur][(rB + 16) * 72 + kg * 8];
            acc[0] = __builtin_amdgcn_mfma_f32_16x16x32_bf16(a, b0, acc[0], 0, 0, 0);
            acc[1] = __builtin_amdgcn_mfma_f32_16x16x32_bf16(a, b1, acc[1], 0, 0, 0);
        }
        if (it + 1 < 32) {
            int nxt = cur ^ 1;
            *(float4*)&As[nxt][srow * 72 + schunk * 8] = ra;
            *(float4*)&Bs[nxt][srow * 72 + schunk * 8] = rb;
        }
    }
    #pragma unroll
    for (int ni = 0; ni < 2; ++ni) {
        int mb = m0 + wm * 16 + quad * 4;
        int nn = n0 + wn * 32 + ni * 16 + col;
        #pragma unroll
        for (int r = 0; r < 4; ++r) {
            int mm = mb + r;
            float sc = bnsc[mm];
            float sh = bnsh[mm];
            outF[((size_t)mm << 10) + nn] = fmaxf(fmaf(acc[ni][r], sc, sh), 0.f);
        }
    }
}

extern "C" void kernel_launch(void* const* d_in, const int* in_sizes, int n_in,
                              void* d_out, int out_size, void* d_ws, size_t ws_size,
                              hipStream_t stream) {
    const float* x     = (const float*)d_in[0];
    const float* w1    = (const float*)d_in[1];
    const float* b1    = (const float*)d_in[2];
    const float* w2    = (const float*)d_in[3];
    const float* b2    = (const float*)d_in[4];
    const float* cw    = (const float*)d_in[5];
    const float* gamma = (const float*)d_in[6];
    const float* beta  = (const float*)d_in[7];
    const float* mu    = (const float*)d_in[8];
    const float* var   = (const float*)d_in[9];
    float* wsf = (float*)d_ws;
    unsigned short* Wb  = (unsigned short*)wsf;                 // 4 MB [1024][2048]
    unsigned short* Bt  = (unsigned short*)(wsf + (1 << 20));   // 4 MB [1024][2048]
    unsigned short* xrb = (unsigned short*)(wsf + (2 << 20));   // 2 MB [p][c]
    unsigned short* U   = (unsigned short*)(wsf + (2 << 20) + (1 << 19)); // 2 MB [c][p]
    float* mean = wsf + (3 << 20);
    float* bnsc = mean + 1024;
    float* bnsh = mean + 2048;
    float* out  = (float*)d_out;

    k_A    <<<256, 256, 0, stream>>>(x, cw, gamma, beta, mu, var, mean, Wb, U, bnsc, bnsh);
    k_prep <<<dim3(16, 16), 256, 0, stream>>>(x, mean, w1, b1, w2, b2, U, xrb, Bt);
    k_attn <<<1024, 256, 0, stream>>>(xrb, Bt);
    k_main <<<256, 512, 0, stream>>>(Wb, Bt, out, bnsc, bnsh);
}

// Round 3
// 112.636 us; speedup vs baseline: 1.1517x; 1.0922x over previous
//
#include <hip/hip_runtime.h>
#include <hip/hip_bf16.h>

// 1x1024x32x32: SE block + separable-gaussian spatial pool + 3x3 local softmax
// attention + 1x1 conv/BN/ReLU.  Round 11: 4 launches.
//   k_A     : per-channel mean + Wb=bf16(W) + BN scale/shift precompute +
//             separable gaussian pool (2 MFMA stages/wave) +
//             SE-MLP layer-1 partials zpart[j][bx] (wave 0; y1 is linear in mean)
//   k_prep  : y1 = relu(reduce(zpart)+b1) (64KB coalesced, replaces 256KB w1
//             re-read per block); y2 slice; xrb transpose; U*y2 -> Bt spatial
//   k_attn  : 3x3 softmax attention on coalesced xrb rows -> Bt attention half
//   k_main  : bf16 MFMA GEMM, BK=128 (16 iters, half the barriers), 8 waves,
//             XCD-swizzled blocks, dbuf LDS, BN + ReLU
// Lessons pinned: grid.sync ~60us/sync on 8 XCDs (r5) — never cooperative.
//                 inline-sigmoid attention = 9.4M scattered 4B loads (r6) —
//                 always transpose once, then read rows.
//                 measured dur includes ~89us fixed harness poison fills (r9) —
//                 only structural work removal moves the needle.
//                 separable pool removal: -6.7us as predicted (r10).

typedef __attribute__((ext_vector_type(8))) short v8s;
typedef __attribute__((ext_vector_type(4))) float v4f;

__device__ __forceinline__ float sigmoidf_(float v) {
    return 1.f / (1.f + __expf(-v));
}
__device__ __forceinline__ unsigned short f2bf(float f) {
    unsigned u = __float_as_uint(f);
    u += 0x7fffu + ((u >> 16) & 1u);
    return (unsigned short)(u >> 16);
}
__device__ __forceinline__ float bf2f(unsigned short s) {
    return __uint_as_float(((unsigned)s) << 16);
}

// ---------------- K1: mean + Wb pack + BN precompute + separable pool + zpart ----------------
__global__ __launch_bounds__(256) void k_A(const float* __restrict__ x,
                                           const float* __restrict__ W,
                                           const float* __restrict__ w1,
                                           const float* __restrict__ gamma,
                                           const float* __restrict__ beta,
                                           const float* __restrict__ mu,
                                           const float* __restrict__ var,
                                           unsigned short* __restrict__ Wb,
                                           unsigned short* __restrict__ U,
                                           float* __restrict__ zpart,
                                           float* __restrict__ bnsc,
                                           float* __restrict__ bnsh) {
    __shared__ unsigned short Gb[32 * 48];       // bf16 normalized 1-D gaussian
    __shared__ unsigned short Xs[4][32 * 48];    // per-wave channel tile bf16
    __shared__ unsigned short Ts[4][32 * 48];    // per-wave stage-1 result bf16
    __shared__ float ms4[4];                     // this block's 4 channel means
    int tid = threadIdx.x, bx = blockIdx.x;
    int wv = tid >> 6, lane = tid & 63;
    // normalized 1-D gaussian row chunk
    {
        int row = tid >> 3, col0 = (tid & 7) << 2;
        float e[4], s = 0.f;
        #pragma unroll
        for (int j = 0; j < 4; ++j) {
            float d = (float)(row - (col0 + j));
            e[j] = __expf(-d * d / 4.5f);
            s += e[j];
        }
        s += __shfl_xor(s, 4, 8);
        s += __shfl_xor(s, 2, 8);
        s += __shfl_xor(s, 1, 8);
        float is = 1.f / s;
        uint2 pk;
        pk.x = (unsigned)f2bf(e[0] * is) | ((unsigned)f2bf(e[1] * is) << 16);
        pk.y = (unsigned)f2bf(e[2] * is) | ((unsigned)f2bf(e[3] * is) << 16);
        *(uint2*)&Gb[row * 48 + col0] = pk;
    }
    // W pack: 2M elements, 8 coalesced chunks
    #pragma unroll
    for (int k = 0; k < 8; ++k) {
        int e = (k << 18) + (bx << 10) + (tid << 2);
        float4 v = *(const float4*)(W + e);
        uint2 pk;
        pk.x = (unsigned)f2bf(v.x) | ((unsigned)f2bf(v.y) << 16);
        pk.y = (unsigned)f2bf(v.z) | ((unsigned)f2bf(v.w) << 16);
        *(uint2*)(Wb + e) = pk;
    }
    // channel c = 4*bx+wv
    int c = (bx << 2) + wv;
    if (lane == 0) {
        float iv = rsqrtf(var[c] + 1e-5f);
        float sc = iv * gamma[c];
        bnsc[c] = sc;
        bnsh[c] = beta[c] - mu[c] * sc;
    }
    // x load + mean + Xs bf16 pack
    const float* xp = x + (size_t)c * 1024;
    float4 vj[4];
    float s = 0.f;
    #pragma unroll
    for (int j = 0; j < 4; ++j) {
        vj[j] = *(const float4*)(xp + (j << 8) + (lane << 2));
        s += vj[j].x + vj[j].y + vj[j].z + vj[j].w;
    }
    #pragma unroll
    for (int o = 32; o; o >>= 1) s += __shfl_down(s, o);
    if (lane == 0) ms4[wv] = s * (1.f / 1024.f);
    #pragma unroll
    for (int j = 0; j < 4; ++j) {
        int h = (j << 3) + (lane >> 3);
        int w0 = (lane & 7) << 2;
        uint2 pk;
        pk.x = (unsigned)f2bf(vj[j].x) | ((unsigned)f2bf(vj[j].y) << 16);
        pk.y = (unsigned)f2bf(vj[j].z) | ((unsigned)f2bf(vj[j].w) << 16);
        *(uint2*)&Xs[wv][h * 48 + w0] = pk;
    }
    __syncthreads();
    // stage 1: T'[pw][h] = sum_w G[pw,w] * X[h,w]
    int colf = lane & 15, quad = lane >> 4;
    v8s ga[2], xbv[2];
    #pragma unroll
    for (int mi = 0; mi < 2; ++mi)
        ga[mi] = *(const v8s*)&Gb[(mi * 16 + colf) * 48 + quad * 8];
    #pragma unroll
    for (int ni = 0; ni < 2; ++ni)
        xbv[ni] = *(const v8s*)&Xs[wv][(ni * 16 + colf) * 48 + quad * 8];
    v4f c1[2][2];
    #pragma unroll
    for (int mi = 0; mi < 2; ++mi)
        #pragma unroll
        for (int ni = 0; ni < 2; ++ni) {
            c1[mi][ni] = (v4f){0.f, 0.f, 0.f, 0.f};
            c1[mi][ni] = __builtin_amdgcn_mfma_f32_16x16x32_bf16(ga[mi], xbv[ni], c1[mi][ni], 0, 0, 0);
        }
    #pragma unroll
    for (int mi = 0; mi < 2; ++mi)
        #pragma unroll
        for (int ni = 0; ni < 2; ++ni)
            #pragma unroll
            for (int r = 0; r < 4; ++r)
                Ts[wv][(mi * 16 + quad * 4 + r) * 48 + ni * 16 + colf] = f2bf(c1[mi][ni][r]);
    __syncthreads();
    // stage 2: S[ph][pw] = sum_h G[ph,h] * T'[pw,h]
    v8s tb[2];
    #pragma unroll
    for (int ni = 0; ni < 2; ++ni)
        tb[ni] = *(const v8s*)&Ts[wv][(ni * 16 + colf) * 48 + quad * 8];
    v4f c2[2][2];
    #pragma unroll
    for (int mi = 0; mi < 2; ++mi)
        #pragma unroll
        for (int ni = 0; ni < 2; ++ni) {
            c2[mi][ni] = (v4f){0.f, 0.f, 0.f, 0.f};
            c2[mi][ni] = __builtin_amdgcn_mfma_f32_16x16x32_bf16(ga[mi], tb[ni], c2[mi][ni], 0, 0, 0);
        }
    #pragma unroll
    for (int mi = 0; mi < 2; ++mi)
        #pragma unroll
        for (int ni = 0; ni < 2; ++ni)
            #pragma unroll
            for (int r = 0; r < 4; ++r)
                U[(size_t)c * 1024 + (mi * 16 + quad * 4 + r) * 32 + ni * 16 + colf] =
                    f2bf(c2[mi][ni][r]);
    // SE-MLP layer-1 partials: zpart[j][bx] = sum_i w1[j][4bx+i]*mean[4bx+i]
    if (wv == 0) {
        float4 wr = *(const float4*)(w1 + (size_t)lane * 1024 + (bx << 2));
        zpart[lane * 256 + bx] = wr.x * ms4[0] + wr.y * ms4[1]
                               + wr.z * ms4[2] + wr.w * ms4[3];
    }
}

// ---------------- K2: y1/y2 from partials + transposes, grid (16,16) x 256 ----------------
__global__ __launch_bounds__(256) void k_prep(const float* __restrict__ x,
                                              const float* __restrict__ zpart,
                                              const float* __restrict__ b1,
                                              const float* __restrict__ w2,
                                              const float* __restrict__ b2,
                                              const unsigned short* __restrict__ U,
                                              unsigned short* __restrict__ xrb,
                                              unsigned short* __restrict__ Bt) {
    __shared__ float y1s[64];
    __shared__ float y2s[64];
    __shared__ float T[64][65];
    int tid = threadIdx.x;
    int p0 = blockIdx.x << 6, c0 = blockIdx.y << 6;
    // y1[j] = relu(b1[j] + sum_bx zpart[j][bx]); 4 lanes per j, float4 loads
    {
        int j = tid >> 2, q = tid & 3;
        const float4* zp = (const float4*)(zpart + j * 256 + q * 64);
        float s = 0.f;
        #pragma unroll
        for (int i = 0; i < 16; ++i) {
            float4 v = zp[i];
            s += v.x + v.y + v.z + v.w;
        }
        s += __shfl_down(s, 2, 4);
        s += __shfl_down(s, 1, 4);
        if (q == 0) y1s[j] = fmaxf(s + b1[j], 0.f);
    }
    __syncthreads();
    // y2[c0+ci] = sigmoid(w2[c0+ci,:] . y1 + b2); 4 lanes per channel
    {
        int ci = tid >> 2, sub = tid & 3;
        float s = 0.f;
        const float* w2r = w2 + (size_t)(c0 + ci) * 64 + sub * 16;
        #pragma unroll
        for (int i = 0; i < 4; ++i) {
            float4 wv4 = *(const float4*)(w2r + (i << 2));
            float4 yv4 = *(const float4*)&y1s[sub * 16 + (i << 2)];
            s += wv4.x * yv4.x + wv4.y * yv4.y + wv4.z * yv4.z + wv4.w * yv4.w;
        }
        s += __shfl_down(s, 2, 4);
        s += __shfl_down(s, 1, 4);
        if (sub == 0) y2s[ci] = sigmoidf_(s + b2[c0 + ci]);
    }
    __syncthreads();
    // pass 1: xrb[p0+prow][c0+cc] = bf16(sigmoid(x[c][p]*y2[c]))
    #pragma unroll
    for (int i = 0; i < 4; ++i) {
        int idx = tid + (i << 8);
        int row = idx >> 4;
        int col = (idx & 15) << 2;
        float sc = y2s[row];
        float4 v = *(const float4*)(x + (size_t)(c0 + row) * 1024 + p0 + col);
        T[col + 0][row] = sigmoidf_(v.x * sc);
        T[col + 1][row] = sigmoidf_(v.y * sc);
        T[col + 2][row] = sigmoidf_(v.z * sc);
        T[col + 3][row] = sigmoidf_(v.w * sc);
    }
    __syncthreads();
    #pragma unroll
    for (int i = 0; i < 4; ++i) {
        int idx = tid + (i << 8);
        int prow = idx >> 4;
        int cc = (idx & 15) << 2;
        uint2 pk;
        pk.x = (unsigned)f2bf(T[prow][cc + 0]) | ((unsigned)f2bf(T[prow][cc + 1]) << 16);
        pk.y = (unsigned)f2bf(T[prow][cc + 2]) | ((unsigned)f2bf(T[prow][cc + 3]) << 16);
        *(uint2*)(xrb + (size_t)(p0 + prow) * 1024 + c0 + cc) = pk;
    }
    __syncthreads();
    // pass 2: Bt[p][1024+c] = bf16(U[c][p] * y2[c])  (spatial half, SE commuted)
    #pragma unroll
    for (int i = 0; i < 4; ++i) {
        int idx = tid + (i << 8);
        int row = idx >> 4;
        int col = (idx & 15) << 2;
        float sc = y2s[row];
        uint2 pk = *(const uint2*)(U + (size_t)(c0 + row) * 1024 + p0 + col);
        T[col + 0][row] = bf2f((unsigned short)(pk.x & 0xffffu)) * sc;
        T[col + 1][row] = bf2f((unsigned short)(pk.x >> 16)) * sc;
        T[col + 2][row] = bf2f((unsigned short)(pk.y & 0xffffu)) * sc;
        T[col + 3][row] = bf2f((unsigned short)(pk.y >> 16)) * sc;
    }
    __syncthreads();
    #pragma unroll
    for (int i = 0; i < 4; ++i) {
        int idx = tid + (i << 8);
        int prow = idx >> 4;
        int cc = (idx & 15) << 2;
        uint2 pk;
        pk.x = (unsigned)f2bf(T[prow][cc + 0]) | ((unsigned)f2bf(T[prow][cc + 1]) << 16);
        pk.y = (unsigned)f2bf(T[prow][cc + 2]) | ((unsigned)f2bf(T[prow][cc + 3]) << 16);
        *(uint2*)(Bt + (size_t)(p0 + prow) * 2048 + 1024 + c0 + cc) = pk;
    }
}

// ---------------- K3: 3x3 softmax attention, 1024 blocks ----------------
__global__ __launch_bounds__(256) void k_attn(const unsigned short* __restrict__ xrb,
                                              unsigned short* __restrict__ Bt) {
    __shared__ struct { unsigned short val[9216]; float part[9][4]; } sm;
    int tid = threadIdx.x;
    int p = blockIdx.x;
    int wv = tid >> 6, lane = tid & 63;
    int h = p >> 5, w = p & 31;
    float ctr[4];
    #pragma unroll
    for (int rem = 0; rem < 9; ++rem) {
        int dh = rem / 3 - 1, dw = rem % 3 - 1;
        bool ok = ((unsigned)(h + dh) < 32u) && ((unsigned)(w + dw) < 32u);
        uint2 v = make_uint2(0u, 0u);
        if (ok)
            v = *(const uint2*)(xrb + (size_t)((h + dh) * 32 + (w + dw)) * 1024 + 4 * tid);
        unsigned short e0 = (unsigned short)(v.x & 0xffffu);
        unsigned short e1 = (unsigned short)(v.x >> 16);
        unsigned short e2 = (unsigned short)(v.y & 0xffffu);
        unsigned short e3 = (unsigned short)(v.y >> 16);
        sm.val[(4 * tid + 0) * 9 + rem] = e0;
        sm.val[(4 * tid + 1) * 9 + rem] = e1;
        sm.val[(4 * tid + 2) * 9 + rem] = e2;
        sm.val[(4 * tid + 3) * 9 + rem] = e3;
        if (rem == 4) {
            ctr[0] = bf2f(e0); ctr[1] = bf2f(e1); ctr[2] = bf2f(e2); ctr[3] = bf2f(e3);
        }
    }
    __syncthreads();
    float vvq[9][4], lg[9];
    #pragma unroll
    for (int q = 0; q < 9; ++q) {
        uint2 pk = *(const uint2*)&sm.val[(q << 10) + 4 * tid];
        vvq[q][0] = bf2f((unsigned short)(pk.x & 0xffffu));
        vvq[q][1] = bf2f((unsigned short)(pk.x >> 16));
        vvq[q][2] = bf2f((unsigned short)(pk.y & 0xffffu));
        vvq[q][3] = bf2f((unsigned short)(pk.y >> 16));
        lg[q] = ctr[0] * vvq[q][0] + ctr[1] * vvq[q][1]
              + ctr[2] * vvq[q][2] + ctr[3] * vvq[q][3];
    }
    #pragma unroll
    for (int q = 0; q < 9; ++q) {
        float s = lg[q];
        #pragma unroll
        for (int o = 32; o; o >>= 1) s += __shfl_down(s, o);
        if (lane == 0) sm.part[q][wv] = s;
    }
    __syncthreads();
    float a9[9], mx = -3.4e38f;
    #pragma unroll
    for (int q = 0; q < 9; ++q) {
        a9[q] = sm.part[q][0] + sm.part[q][1] + sm.part[q][2] + sm.part[q][3];
        mx = fmaxf(mx, a9[q]);
    }
    float se = 0.f;
    #pragma unroll
    for (int q = 0; q < 9; ++q) { a9[q] = __expf(a9[q] - mx); se += a9[q]; }
    float inv = 1.f / se;
    float o4[4] = {0.f, 0.f, 0.f, 0.f};
    #pragma unroll
    for (int q = 0; q < 9; ++q) {
        float a = a9[q] * inv;
        #pragma unroll
        for (int j = 0; j < 4; ++j) o4[j] += a * vvq[q][j];
    }
    uint2 pk;
    pk.x = (unsigned)f2bf(o4[0]) | ((unsigned)f2bf(o4[1]) << 16);
    pk.y = (unsigned)f2bf(o4[2]) | ((unsigned)f2bf(o4[3]) << 16);
    *(uint2*)(Bt + (size_t)p * 2048 + 4 * tid) = pk;
}

// ---------------- K4: main GEMM, BK=128, XCD-swizzled, 8 waves, dbuf LDS ----------------
__global__ __launch_bounds__(512) void k_main(
    const unsigned short* __restrict__ A, const unsigned short* __restrict__ B,
    float* __restrict__ outF,
    const float* __restrict__ bnsc, const float* __restrict__ bnsh) {
    __shared__ unsigned short As[2][64 * 136];
    __shared__ unsigned short Bs[2][64 * 136];
    const int K = 2048;
    int tid = threadIdx.x;
    // XCD swizzle: give XCD k a 4x8 tile rectangle (1MB A + 2MB B L2 footprint)
    int bid = blockIdx.x;
    int xcd = bid & 7, idx = bid >> 3;
    int by = ((xcd >> 1) << 2) + (idx >> 3);
    int bxn = ((xcd & 1) << 3) + (idx & 7);
    int m0 = by << 6, n0 = bxn << 6;
    int wv = tid >> 6, lane = tid & 63;
    int wm = wv & 3, wn = wv >> 2;          // 4 (M) x 2 (N) wave grid
    int col = lane & 15, quad = lane >> 4;
    int srow = tid >> 3;                    // stage row 0..63
    int schunk = tid & 7;                   // stage chunks schunk, schunk+8
    v4f acc[2];
    acc[0] = (v4f){0.f, 0.f, 0.f, 0.f};
    acc[1] = (v4f){0.f, 0.f, 0.f, 0.f};

    const float4* pa = (const float4*)(A + (size_t)(m0 + srow) * K + schunk * 8);
    const float4* pb = (const float4*)(B + (size_t)(n0 + srow) * K + schunk * 8);
    float4 ra0 = pa[0], ra1 = pa[8], rb0 = pb[0], rb1 = pb[8];
    *(float4*)&As[0][srow * 136 + schunk * 8] = ra0;
    *(float4*)&As[0][srow * 136 + schunk * 8 + 64] = ra1;
    *(float4*)&Bs[0][srow * 136 + schunk * 8] = rb0;
    *(float4*)&Bs[0][srow * 136 + schunk * 8 + 64] = rb1;
    for (int it = 0; it < 16; ++it) {
        __syncthreads();
        int cur = it & 1;
        if (it + 1 < 16) {
            int k0 = (it + 1) << 7;
            pa = (const float4*)(A + (size_t)(m0 + srow) * K + k0 + schunk * 8);
            pb = (const float4*)(B + (size_t)(n0 + srow) * K + k0 + schunk * 8);
            ra0 = pa[0]; ra1 = pa[8];
            rb0 = pb[0]; rb1 = pb[8];
        }
        #pragma unroll
        for (int ks = 0; ks < 4; ++ks) {
            int kg = ks * 4 + quad;
            int rA = wm * 16 + col;
            int rB = wn * 32 + col;
            v8s a  = *(const v8s*)&As[cur][rA * 136 + kg * 8];
            v8s b0 = *(const v8s*)&Bs[cur][rB * 136 + kg * 8];
            v8s b1 = *(const v8s*)&Bs[cur][(rB + 16) * 136 + kg * 8];
            acc[0] = __builtin_amdgcn_mfma_f32_16x16x32_bf16(a, b0, acc[0], 0, 0, 0);
            acc[1] = __builtin_amdgcn_mfma_f32_16x16x32_bf16(a, b1, acc[1], 0, 0, 0);
        }
        if (it + 1 < 16) {
            int nxt = cur ^ 1;
            *(float4*)&As[nxt][srow * 136 + schunk * 8] = ra0;
            *(float4*)&As[nxt][srow * 136 + schunk * 8 + 64] = ra1;
            *(float4*)&Bs[nxt][srow * 136 + schunk * 8] = rb0;
            *(float4*)&Bs[nxt][srow * 136 + schunk * 8 + 64] = rb1;
        }
    }
    #pragma unroll
    for (int ni = 0; ni < 2; ++ni) {
        int mb = m0 + wm * 16 + quad * 4;
        int nn = n0 + wn * 32 + ni * 16 + col;
        #pragma unroll
        for (int r = 0; r < 4; ++r) {
            int mm = mb + r;
            float sc = bnsc[mm];
            float sh = bnsh[mm];
            outF[((size_t)mm << 10) + nn] = fmaxf(fmaf(acc[ni][r], sc, sh), 0.f);
        }
    }
}

extern "C" void kernel_launch(void* const* d_in, const int* in_sizes, int n_in,
                              void* d_out, int out_size, void* d_ws, size_t ws_size,
                              hipStream_t stream) {
    const float* x     = (const float*)d_in[0];
    const float* w1    = (const float*)d_in[1];
    const float* b1    = (const float*)d_in[2];
    const float* w2    = (const float*)d_in[3];
    const float* b2    = (const float*)d_in[4];
    const float* cw    = (const float*)d_in[5];
    const float* gamma = (const float*)d_in[6];
    const float* beta  = (const float*)d_in[7];
    const float* mu    = (const float*)d_in[8];
    const float* var   = (const float*)d_in[9];
    float* wsf = (float*)d_ws;
    unsigned short* Wb  = (unsigned short*)wsf;                 // 4 MB [1024][2048]
    unsigned short* Bt  = (unsigned short*)(wsf + (1 << 20));   // 4 MB [1024][2048]
    unsigned short* xrb = (unsigned short*)(wsf + (2 << 20));   // 2 MB [p][c]
    unsigned short* U   = (unsigned short*)(wsf + (2 << 20) + (1 << 19)); // 2 MB [c][p]
    float* zpart = wsf + (3 << 20);                             // 64 KB [64][256]
    float* bnsc  = zpart + 16384;
    float* bnsh  = bnsc + 1024;
    float* out  = (float*)d_out;

    k_A    <<<256, 256, 0, stream>>>(x, cw, w1, gamma, beta, mu, var, Wb, U, zpart, bnsc, bnsh);
    k_prep <<<dim3(16, 16), 256, 0, stream>>>(x, zpart, b1, w2, b2, U, xrb, Bt);
    k_attn <<<1024, 256, 0, stream>>>(xrb, Bt);
    k_main <<<256, 512, 0, stream>>>(Wb, Bt, out, bnsc, bnsh);
}